// Round 6
// baseline (1370.045 us; speedup 1.0000x reference)
//
#include <hip/hip_runtime.h>
#include <hip/hip_bf16.h>

#define NN 16384
#define NE 131072
#define L 256
#define SSTEPS 4
#define OUTD 128

typedef __attribute__((ext_vector_type(8))) short bf16x8;
typedef __attribute__((ext_vector_type(4))) float f32x4;

__device__ __forceinline__ short f2bs(float f) {
  unsigned u = __builtin_bit_cast(unsigned, f);
  u = (u + 0x7fffu + ((u >> 16) & 1u)) >> 16;
  return (short)u;
}
__device__ __forceinline__ float bs2f(short s) {
  unsigned u = ((unsigned)(unsigned short)s) << 16;
  return __builtin_bit_cast(float, u);
}
__device__ __forceinline__ float wave_sum(float v) {
#pragma unroll
  for (int o = 32; o > 0; o >>= 1) v += __shfl_xor(v, o);
  return v;
}

// Store one 16x16 C-tile (f32x4 per lane) into swizzled bf16 LDS [64][256]
// (row stride 512B). byte ^= (row&7)<<4.
__device__ __forceinline__ void store_tile(short* hs, int l, int mi, int nb,
                                           f32x4 v) {
  const int lm = l & 15, g = l >> 4;
#pragma unroll
  for (int i = 0; i < 4; ++i) {
    const float mine = v[i];
    const float part = __shfl_xor(mine, 1);
    if ((l & 1) == 0) {
      const int row = mi * 16 + g * 4 + i;
      const int col = nb + lm;  // even
      const unsigned pk = (unsigned)(unsigned short)f2bs(mine) |
                          ((unsigned)(unsigned short)f2bs(part) << 16);
      const int off = (row * 512 + col * 2) ^ ((row & 7) << 4);
      *(unsigned*)((char*)hs + off) = pk;
    }
  }
}

// GEMM from swizzled bf16 LDS h[64][256] (512B stride) x packed W (K=256).
template <int NT>
__device__ __forceinline__ void gemm2_lds(const short* __restrict__ Wp,
                                          int Ncols, const short* hs, int n0,
                                          int l, f32x4 acc[4][NT]) {
  const int lm = l & 15, g = l >> 4;
#pragma unroll
  for (int kc = 0; kc < 8; ++kc) {
    bf16x8 a[4];
#pragma unroll
    for (int mi = 0; mi < 4; ++mi) {
      const int row = mi * 16 + lm;
      const int off = (row * 512 + kc * 64 + g * 16) ^ ((row & 7) << 4);
      a[mi] = *(const bf16x8*)((const char*)hs + off);
    }
#pragma unroll
    for (int ni = 0; ni < NT; ++ni) {
      const int n = n0 + ni * 16 + lm;
      bf16x8 b = *(const bf16x8*)(Wp + ((size_t)kc * Ncols + n) * 32 + g * 8);
#pragma unroll
      for (int mi = 0; mi < 4; ++mi)
        acc[mi][ni] =
            __builtin_amdgcn_mfma_f32_16x16x32_bf16(a[mi], b, acc[mi][ni], 0, 0, 0);
    }
  }
}

// Pack fp32 weight [K][N] (cnt stacked) into bf16 Wp[k/32][n][k%32].
__global__ void pack_w(const float* __restrict__ src, short* __restrict__ dst,
                       int K, int N, int cnt) {
  const size_t total = (size_t)K * N * cnt;
  for (size_t i = (size_t)blockIdx.x * blockDim.x + threadIdx.x; i < total;
       i += (size_t)gridDim.x * blockDim.x) {
    const size_t mat = i / ((size_t)K * N);
    const int rem = (int)(i - mat * (size_t)K * N);
    const int k = rem / N, n = rem - k * N;
    dst[mat * (size_t)K * N + ((size_t)(k >> 5) * N + n) * 32 + (k & 31)] =
        f2bs(src[i]);
  }
}

// Layer-1 MFMA over one staged 128-K chunk in As (row stride 256B, swizzled).
__device__ __forceinline__ void mfma_chunk(const short* __restrict__ As,
                                           const short* __restrict__ W0p,
                                           int kcg_base, int w, int l,
                                           f32x4 acc[4][4]) {
  const int lm = l & 15, g = l >> 4;
#pragma unroll
  for (int kc = 0; kc < 4; ++kc) {
    bf16x8 a[4];
#pragma unroll
    for (int mi = 0; mi < 4; ++mi) {
      const int row = mi * 16 + lm;
      const int off = (row * 256 + kc * 64 + g * 16) ^ ((row & 7) << 4);
      a[mi] = *(const bf16x8*)((const char*)As + off);
    }
#pragma unroll
    for (int ni = 0; ni < 4; ++ni) {
      const int n = w * 64 + ni * 16 + lm;
      bf16x8 b =
          *(const bf16x8*)(W0p + ((size_t)(kcg_base + kc) * L + n) * 32 + g * 8);
#pragma unroll
      for (int mi = 0; mi < 4; ++mi)
        acc[mi][ni] =
            __builtin_amdgcn_mfma_f32_16x16x32_bf16(a[mi], b, acc[mi][ni], 0, 0, 0);
    }
  }
}

// ---------------------------------------------------------------------------
// CSR build (deterministic: per-node lists sorted ascending by edge id)
// ---------------------------------------------------------------------------
__global__ void csr_hist(const int* __restrict__ recv, int* __restrict__ deg) {
  const int e = blockIdx.x * 256 + threadIdx.x;
  atomicAdd(&deg[recv[e]], 1);
}
__global__ __launch_bounds__(256) void csr_scan(const int* __restrict__ deg,
                                                int* __restrict__ start,
                                                int* __restrict__ cursor) {
  __shared__ int part[256];
  const int t = threadIdx.x;
  int s = 0;
  for (int i = 0; i < NN / 256; ++i) s += deg[t * (NN / 256) + i];
  part[t] = s;
  __syncthreads();
  if (t == 0) {
    int acc = 0;
    for (int i = 0; i < 256; ++i) {
      const int v = part[i];
      part[i] = acc;
      acc += v;
    }
  }
  __syncthreads();
  int acc = part[t];
  for (int i = 0; i < NN / 256; ++i) {
    const int n = t * (NN / 256) + i;
    start[n] = acc;
    cursor[n] = acc;
    acc += deg[n];
  }
  if (t == 255) start[NN] = acc;
}
__global__ void csr_scatter(const int* __restrict__ recv,
                            int* __restrict__ cursor, int* __restrict__ elist) {
  const int e = blockIdx.x * 256 + threadIdx.x;
  const int p = atomicAdd(&cursor[recv[e]], 1);
  elist[p] = e;
}
__global__ void csr_sort(const int* __restrict__ start, int* __restrict__ elist) {
  const int n = blockIdx.x * blockDim.x + threadIdx.x;
  if (n >= NN) return;
  const int b = start[n], e = start[n + 1];
  for (int i = b + 1; i < e; ++i) {
    const int v = elist[i];
    int j = i - 1;
    while (j >= b && elist[j] > v) {
      elist[j + 1] = elist[j];
      --j;
    }
    elist[j + 1] = v;
  }
}

// ---------------------------------------------------------------------------
// agg gather: agg_b[n] = bf16( sum_{e in CSR[n]} new_e[e] )  (fp32 accum)
// 32 lanes x bf16x8 cover one 256-col row; 2 rows per wave-iteration.
// ---------------------------------------------------------------------------
__global__ __launch_bounds__(256) void agg_gather(
    const short* __restrict__ new_e, const int* __restrict__ start,
    const int* __restrict__ elist, short* __restrict__ agg_b) {
  const int t = threadIdx.x, w = t >> 6, l = t & 63;
  const int half = l >> 5, lc = l & 31;
  const int n0 = blockIdx.x * 64;
  for (int i = 0; i < 8; ++i) {
    const int n = n0 + w * 16 + i * 2 + half;
    const int b = start[n], e = start[n + 1];
    float acc[8] = {0.f, 0.f, 0.f, 0.f, 0.f, 0.f, 0.f, 0.f};
    for (int j = b; j < e; ++j) {
      const int eid = elist[j];
      const bf16x8 v = *(const bf16x8*)(new_e + (size_t)eid * L + lc * 8);
#pragma unroll
      for (int k = 0; k < 8; ++k) acc[k] += bs2f(v[k]);
    }
    bf16x8 o;
#pragma unroll
    for (int k = 0; k < 8; ++k) o[k] = f2bs(acc[k]);
    *(bf16x8*)(agg_b + (size_t)n * L + lc * 8) = o;
  }
}

// ---------------------------------------------------------------------------
// Shared epilogue piece: per-row LN stats from swizzled y tile -> stats LDS.
// Wave w reduces rows w*16..w*16+15.
// ---------------------------------------------------------------------------
__device__ __forceinline__ void ln_stats(const short* smem, float2* stats_s,
                                         int w, int l) {
#pragma unroll 4
  for (int rr = 0; rr < 16; ++rr) {
    const int r = w * 16 + rr;
    float v[4];
#pragma unroll
    for (int j = 0; j < 4; ++j) {
      const int off = (r * 512 + (l + 64 * j) * 2) ^ ((r & 7) << 4);
      v[j] = bs2f(*(const short*)((const char*)smem + off));
    }
    const float mu = wave_sum(v[0] + v[1] + v[2] + v[3]) * (1.f / 256.f);
    float sq = 0.f;
#pragma unroll
    for (int j = 0; j < 4; ++j) {
      const float d = v[j] - mu;
      sq += d * d;
    }
    const float rstd = rsqrtf(wave_sum(sq) * (1.f / 256.f) + 1e-6f);
    if (l == 0) stats_s[r] = make_float2(mu, rstd);
  }
}

// read y fragment (8 cols) from swizzled LDS and apply LN
__device__ __forceinline__ void ln_apply(const short* smem, int row, int col0,
                                         float mu, float rstd,
                                         const float* __restrict__ ls,
                                         const float* __restrict__ lb,
                                         float ne[8]) {
  const int off = (row * 512 + col0 * 2) ^ ((row & 7) << 4);
  const bf16x8 y = *(const bf16x8*)((const char*)smem + off);
  const float4 lsA = *(const float4*)(ls + col0);
  const float4 lsB = *(const float4*)(ls + col0 + 4);
  const float4 lbA = *(const float4*)(lb + col0);
  const float4 lbB = *(const float4*)(lb + col0 + 4);
  const float lsv[8] = {lsA.x, lsA.y, lsA.z, lsA.w, lsB.x, lsB.y, lsB.z, lsB.w};
  const float lbv[8] = {lbA.x, lbA.y, lbA.z, lbA.w, lbB.x, lbB.y, lbB.z, lbB.w};
#pragma unroll
  for (int k = 0; k < 8; ++k)
    ne[k] = (bs2f(y[k]) - mu) * rstd * lsv[k] + lbv[k];
}

// ---------------------------------------------------------------------------
// Edge step: X=[edges_b|nodes_b[snd]|nodes_b[rcv]] (768 bf16) -> MFMA MLP ->
// LN -> edges_b += ne (residual from regs); new_e = ne. Vector epilogue.
// ---------------------------------------------------------------------------
__global__ __launch_bounds__(256) void edge_step_mfma(
    const short* __restrict__ nodes_b, short* __restrict__ edges_b,
    short* __restrict__ new_e, const int* __restrict__ senders,
    const int* __restrict__ receivers, const short* __restrict__ W0p,
    const float* __restrict__ b0, const short* __restrict__ W1p,
    const float* __restrict__ b1, const float* __restrict__ ls,
    const float* __restrict__ lb) {
  __shared__ short smem[64 * 256];  // 32KB: As[2][64][128] then h/y[64][256]
  __shared__ float2 stats_s[64];
  __shared__ int sn_s[64], rc_s[64];
  const int t = threadIdx.x, w = t >> 6, l = t & 63;
  const int lm = l & 15, g = l >> 4;
  const int tr = t >> 4, seg = t & 15;
  const int e0 = blockIdx.x * 64;
  short* As0 = smem;
  short* As1 = smem + 8192;

  if (t < 64) sn_s[t] = senders[e0 + t];
  else if (t < 128) rc_s[t - 64] = receivers[e0 + t - 64];

  bf16x8 o8[4];
  bf16x8 old0[4], old1[4];  // residual stash (edge cols 0..127 / 128..255)
  // prologue: chunk 0 (edges, bf16 cols 0..127)
#pragma unroll
  for (int p = 0; p < 4; ++p) {
    o8[p] = *(const bf16x8*)(edges_b + (size_t)(e0 + p * 16 + tr) * L + seg * 8);
    old0[p] = o8[p];
  }
#pragma unroll
  for (int p = 0; p < 4; ++p) {
    const int row = p * 16 + tr;
    const int off = (row * 256 + seg * 16) ^ ((row & 7) << 4);
    *(bf16x8*)((char*)As0 + off) = o8[p];
  }
  __syncthreads();

  f32x4 acc[4][4] = {};
#pragma unroll
  for (int c = 0; c < 6; ++c) {
    if (c + 1 < 6) {  // issue next chunk's global loads (hide under MFMA)
      const int cn = c + 1;
      const short* src;
      const int* ridx = nullptr;
      int cb, rb = 0;
      if (cn < 2) { src = edges_b; cb = cn * 128; rb = e0; }
      else if (cn < 4) { src = nodes_b; cb = (cn - 2) * 128; ridx = sn_s; }
      else { src = nodes_b; cb = (cn - 4) * 128; ridx = rc_s; }
#pragma unroll
      for (int p = 0; p < 4; ++p) {
        const int row = p * 16 + tr;
        const size_t gr = ridx ? (size_t)ridx[row] : (size_t)(rb + row);
        o8[p] = *(const bf16x8*)(src + gr * L + cb + seg * 8);
      }
      if (cn == 1) {
#pragma unroll
        for (int p = 0; p < 4; ++p) old1[p] = o8[p];
      }
    }
    mfma_chunk((c & 1) ? As1 : As0, W0p, c * 4, w, l, acc);
    if (c + 1 < 6) {
      short* dbuf = (c & 1) ? As0 : As1;
#pragma unroll
      for (int p = 0; p < 4; ++p) {
        const int row = p * 16 + tr;
        const int off = (row * 256 + seg * 16) ^ ((row & 7) << 4);
        *(bf16x8*)((char*)dbuf + off) = o8[p];
      }
    }
    __syncthreads();
  }

  // bias + relu -> h in smem (viewed as [64][256], 512B stride)
#pragma unroll
  for (int ni = 0; ni < 4; ++ni) {
    const float bia = b0[w * 64 + ni * 16 + lm];
#pragma unroll
    for (int mi = 0; mi < 4; ++mi) {
      f32x4 v = acc[mi][ni];
#pragma unroll
      for (int i = 0; i < 4; ++i) v[i] = fmaxf(v[i] + bia, 0.f);
      store_tile(smem, l, mi, w * 64 + ni * 16, v);
    }
  }
  __syncthreads();

  f32x4 acc2[4][4] = {};
  gemm2_lds<4>(W1p, L, smem, w * 64, l, acc2);
  __syncthreads();
#pragma unroll
  for (int ni = 0; ni < 4; ++ni) {
    const float bia = b1[w * 64 + ni * 16 + lm];
#pragma unroll
    for (int mi = 0; mi < 4; ++mi) {
      f32x4 v = acc2[mi][ni];
#pragma unroll
      for (int i = 0; i < 4; ++i) v[i] += bia;
      store_tile(smem, l, mi, w * 64 + ni * 16, v);
    }
  }
  __syncthreads();

  ln_stats(smem, stats_s, w, l);
  __syncthreads();

  // vector output: thread handles rows p*16+tr, cols seg*8 (+cc*128)
#pragma unroll
  for (int p = 0; p < 4; ++p) {
    const int row = p * 16 + tr;
    const size_t e = (size_t)(e0 + row);
    const float2 st = stats_s[row];
#pragma unroll
    for (int cc = 0; cc < 2; ++cc) {
      const int col0 = cc * 128 + seg * 8;
      float ne[8];
      ln_apply(smem, row, col0, st.x, st.y, ls, lb, ne);
      const bf16x8 old = cc ? old1[p] : old0[p];
      bf16x8 nb, eb;
#pragma unroll
      for (int k = 0; k < 8; ++k) {
        nb[k] = f2bs(ne[k]);
        eb[k] = f2bs(bs2f(old[k]) + ne[k]);
      }
      *(bf16x8*)(new_e + e * L + col0) = nb;
      *(bf16x8*)(edges_b + e * L + col0) = eb;
    }
  }
}

// ---------------------------------------------------------------------------
// Node step: X=[nodes_b|agg_b] (512 bf16) -> MFMA MLP -> LN ->
// nodes_f += ne (fp32 master) ; nodes_b = bf16(nodes_f). Vector epilogue.
// ---------------------------------------------------------------------------
__global__ __launch_bounds__(256) void node_step_mfma(
    float* __restrict__ nodes_f, short* __restrict__ nodes_b,
    const short* __restrict__ agg_b, const short* __restrict__ W0p,
    const float* __restrict__ b0, const short* __restrict__ W1p,
    const float* __restrict__ b1, const float* __restrict__ ls,
    const float* __restrict__ lb) {
  __shared__ short smem[64 * 256];
  __shared__ float2 stats_s[64];
  const int t = threadIdx.x, w = t >> 6, l = t & 63;
  const int lm = l & 15, g = l >> 4;
  const int tr = t >> 4, seg = t & 15;
  const int n0 = blockIdx.x * 64;
  short* As0 = smem;
  short* As1 = smem + 8192;

  bf16x8 o8[4];
#pragma unroll
  for (int p = 0; p < 4; ++p)
    o8[p] = *(const bf16x8*)(nodes_b + (size_t)(n0 + p * 16 + tr) * L + seg * 8);
#pragma unroll
  for (int p = 0; p < 4; ++p) {
    const int row = p * 16 + tr;
    const int off = (row * 256 + seg * 16) ^ ((row & 7) << 4);
    *(bf16x8*)((char*)As0 + off) = o8[p];
  }
  __syncthreads();

  f32x4 acc[4][4] = {};
#pragma unroll
  for (int c = 0; c < 4; ++c) {
    if (c + 1 < 4) {
      const int cn = c + 1;
      const short* src = (cn < 2) ? nodes_b : agg_b;
      const int cb = (cn & 1) * 128;
#pragma unroll
      for (int p = 0; p < 4; ++p)
        o8[p] = *(const bf16x8*)(src + (size_t)(n0 + p * 16 + tr) * L + cb + seg * 8);
    }
    mfma_chunk((c & 1) ? As1 : As0, W0p, c * 4, w, l, acc);
    if (c + 1 < 4) {
      short* dbuf = (c & 1) ? As0 : As1;
#pragma unroll
      for (int p = 0; p < 4; ++p) {
        const int row = p * 16 + tr;
        const int off = (row * 256 + seg * 16) ^ ((row & 7) << 4);
        *(bf16x8*)((char*)dbuf + off) = o8[p];
      }
    }
    __syncthreads();
  }

#pragma unroll
  for (int ni = 0; ni < 4; ++ni) {
    const float bia = b0[w * 64 + ni * 16 + lm];
#pragma unroll
    for (int mi = 0; mi < 4; ++mi) {
      f32x4 v = acc[mi][ni];
#pragma unroll
      for (int i = 0; i < 4; ++i) v[i] = fmaxf(v[i] + bia, 0.f);
      store_tile(smem, l, mi, w * 64 + ni * 16, v);
    }
  }
  __syncthreads();

  f32x4 acc2[4][4] = {};
  gemm2_lds<4>(W1p, L, smem, w * 64, l, acc2);
  __syncthreads();
#pragma unroll
  for (int ni = 0; ni < 4; ++ni) {
    const float bia = b1[w * 64 + ni * 16 + lm];
#pragma unroll
    for (int mi = 0; mi < 4; ++mi) {
      f32x4 v = acc2[mi][ni];
#pragma unroll
      for (int i = 0; i < 4; ++i) v[i] += bia;
      store_tile(smem, l, mi, w * 64 + ni * 16, v);
    }
  }
  __syncthreads();

  ln_stats(smem, stats_s, w, l);
  __syncthreads();

#pragma unroll
  for (int p = 0; p < 4; ++p) {
    const int row = p * 16 + tr;
    const size_t n = (size_t)(n0 + row);
    const float2 st = stats_s[row];
#pragma unroll
    for (int cc = 0; cc < 2; ++cc) {
      const int col0 = cc * 128 + seg * 8;
      float ne[8];
      ln_apply(smem, row, col0, st.x, st.y, ls, lb, ne);
      float* nf = nodes_f + n * L + col0;
      float4 fA = *(const float4*)nf;
      float4 fB = *(const float4*)(nf + 4);
      float nv[8] = {fA.x + ne[0], fA.y + ne[1], fA.z + ne[2], fA.w + ne[3],
                     fB.x + ne[4], fB.y + ne[5], fB.z + ne[6], fB.w + ne[7]};
      *(float4*)nf = make_float4(nv[0], nv[1], nv[2], nv[3]);
      *(float4*)(nf + 4) = make_float4(nv[4], nv[5], nv[6], nv[7]);
      bf16x8 nb;
#pragma unroll
      for (int k = 0; k < 8; ++k) nb[k] = f2bs(nv[k]);
      *(bf16x8*)(nodes_b + n * L + col0) = nb;
    }
  }
}

// ---------------------------------------------------------------------------
// Embedder: layer1 (K1->256, VALU) -> h in LDS -> MFMA layer2 -> LN -> dst
// WF32: also write fp32 master (nodes); always writes bf16. Vector epilogue.
// ---------------------------------------------------------------------------
template <int K1, bool WF32>
__global__ __launch_bounds__(256) void embed_mfma(
    const float* __restrict__ x, const float* __restrict__ W0,
    const float* __restrict__ b0, const short* __restrict__ W1p,
    const float* __restrict__ b1, const float* __restrict__ ls,
    const float* __restrict__ lb, float* __restrict__ dst_f,
    short* __restrict__ dst_b) {
  __shared__ short hs[64 * 256];
  __shared__ float2 stats_s[64];
  __shared__ float xs[64][K1];
  const int t = threadIdx.x, w = t >> 6, l = t & 63;
  const int tr = t >> 4, seg = t & 15;
  const int r0 = blockIdx.x * 64;

  if (t < 64 * K1) xs[t / K1][t % K1] = x[(size_t)r0 * K1 + t];
  __syncthreads();

  float wc[K1];
#pragma unroll
  for (int k = 0; k < K1; ++k) wc[k] = W0[k * L + t];
  const float bb = b0[t];
  for (int r = 0; r < 64; ++r) {
    float h = bb;
#pragma unroll
    for (int k = 0; k < K1; ++k) h = fmaf(xs[r][k], wc[k], h);
    h = fmaxf(h, 0.f);
    const int off = (r * 512 + t * 2) ^ ((r & 7) << 4);
    *(short*)((char*)hs + off) = f2bs(h);
  }
  __syncthreads();

  const int lm = l & 15;
  f32x4 acc2[4][4] = {};
  gemm2_lds<4>(W1p, L, hs, w * 64, l, acc2);
  __syncthreads();
#pragma unroll
  for (int ni = 0; ni < 4; ++ni) {
    const float bia = b1[w * 64 + ni * 16 + lm];
#pragma unroll
    for (int mi = 0; mi < 4; ++mi) {
      f32x4 v = acc2[mi][ni];
#pragma unroll
      for (int i = 0; i < 4; ++i) v[i] += bia;
      store_tile(hs, l, mi, w * 64 + ni * 16, v);
    }
  }
  __syncthreads();

  ln_stats(hs, stats_s, w, l);
  __syncthreads();

#pragma unroll
  for (int p = 0; p < 4; ++p) {
    const int row = p * 16 + tr;
    const size_t n = (size_t)(r0 + row);
    const float2 st = stats_s[row];
#pragma unroll
    for (int cc = 0; cc < 2; ++cc) {
      const int col0 = cc * 128 + seg * 8;
      float ne[8];
      ln_apply(hs, row, col0, st.x, st.y, ls, lb, ne);
      bf16x8 nb;
#pragma unroll
      for (int k = 0; k < 8; ++k) nb[k] = f2bs(ne[k]);
      *(bf16x8*)(dst_b + n * L + col0) = nb;
      if (WF32) {
        float* df = dst_f + n * L + col0;
        *(float4*)df = make_float4(ne[0], ne[1], ne[2], ne[3]);
        *(float4*)(df + 4) = make_float4(ne[4], ne[5], ne[6], ne[7]);
      }
    }
  }
}

// ---------------------------------------------------------------------------
// Decoder: nodes_b (256 bf16) -> MFMA 256 relu -> MFMA 128 -> out (fp32)
// ---------------------------------------------------------------------------
__global__ __launch_bounds__(256) void decoder_mfma(
    const short* __restrict__ nodes_b, const short* __restrict__ W0p,
    const float* __restrict__ b0, const short* __restrict__ W1p,
    const float* __restrict__ b1, float* __restrict__ out) {
  __shared__ short hs[64 * 256];
  const int t = threadIdx.x, w = t >> 6, l = t & 63;
  const int lm = l & 15, g = l >> 4;
  const int n0 = blockIdx.x * 64;

  const short* baseA[4];
#pragma unroll
  for (int mi = 0; mi < 4; ++mi)
    baseA[mi] = nodes_b + (size_t)(n0 + mi * 16 + lm) * L;

  f32x4 acc[4][4] = {};
#pragma unroll
  for (int kc = 0; kc < 8; ++kc) {
    const int koff = kc * 32 + g * 8;
    bf16x8 a[4];
#pragma unroll
    for (int mi = 0; mi < 4; ++mi) a[mi] = *(const bf16x8*)(baseA[mi] + koff);
#pragma unroll
    for (int ni = 0; ni < 4; ++ni) {
      const int n = w * 64 + ni * 16 + lm;
      bf16x8 b = *(const bf16x8*)(W0p + ((size_t)kc * L + n) * 32 + g * 8);
#pragma unroll
      for (int mi = 0; mi < 4; ++mi)
        acc[mi][ni] = __builtin_amdgcn_mfma_f32_16x16x32_bf16(a[mi], b,
                                                             acc[mi][ni],
                                                             0, 0, 0);
    }
  }
#pragma unroll
  for (int ni = 0; ni < 4; ++ni) {
    const float bia = b0[w * 64 + ni * 16 + lm];
#pragma unroll
    for (int mi = 0; mi < 4; ++mi) {
      f32x4 v = acc[mi][ni];
#pragma unroll
      for (int i = 0; i < 4; ++i) v[i] = fmaxf(v[i] + bia, 0.f);
      store_tile(hs, l, mi, w * 64 + ni * 16, v);
    }
  }
  __syncthreads();

  f32x4 acc2[4][2] = {};
  gemm2_lds<2>(W1p, OUTD, hs, w * 32, l, acc2);

  float b14[2];
#pragma unroll
  for (int ni = 0; ni < 2; ++ni) b14[ni] = b1[w * 32 + ni * 16 + lm];
#pragma unroll
  for (int mi = 0; mi < 4; ++mi)
#pragma unroll
    for (int ni = 0; ni < 2; ++ni)
#pragma unroll
      for (int i = 0; i < 4; ++i) {
        const int row = n0 + mi * 16 + g * 4 + i;
        const int col = w * 32 + ni * 16 + lm;
        out[(size_t)row * OUTD + col] = acc2[mi][ni][i] + b14[ni];
      }
}

// ---------------------------------------------------------------------------
extern "C" void kernel_launch(void* const* d_in, const int* in_sizes, int n_in,
                              void* d_out, int out_size, void* d_ws,
                              size_t ws_size, hipStream_t stream) {
  const float* node_feats = (const float*)d_in[0];
  const float* edge_feats = (const float*)d_in[1];
  const int* senders = (const int*)d_in[2];
  const int* receivers = (const int*)d_in[3];
  auto f = [&](int i) { return (const float*)d_in[i]; };

  char* p = (char*)d_ws;
  auto alloc = [&](size_t bytes) {
    char* q = p;
    p += (bytes + 255) & ~(size_t)255;
    return q;
  };
  float* nodes_f = (float*)alloc((size_t)NN * L * 4);   // 16 MB
  short* nodes_b = (short*)alloc((size_t)NN * L * 2);   // 8 MB
  short* edges_b = (short*)alloc((size_t)NE * L * 2);   // 67 MB
  short* new_e = (short*)alloc((size_t)NE * L * 2);     // 67 MB
  short* agg_b = (short*)alloc((size_t)NN * L * 2);     // 8 MB
  int* deg = (int*)alloc((size_t)NN * 4);
  int* start = (int*)alloc((size_t)(NN + 16) * 4);
  int* cursor = (int*)alloc((size_t)NN * 4);
  int* elist = (int*)alloc((size_t)NE * 4);
  short* en_W1p = (short*)alloc(65536 * 2);
  short* ee_W1p = (short*)alloc(65536 * 2);
  short* pe_W0p = (short*)alloc((size_t)4 * 768 * 256 * 2);
  short* pe_W1p = (short*)alloc((size_t)4 * 65536 * 2);
  short* pn_W0p = (short*)alloc((size_t)4 * 512 * 256 * 2);
  short* pn_W1p = (short*)alloc((size_t)4 * 65536 * 2);
  short* dn_W0p = (short*)alloc(65536 * 2);
  short* dn_W1p = (short*)alloc(32768 * 2);

  // CSR build (deterministic after per-node sort)
  hipMemsetAsync(deg, 0, (size_t)NN * 4, stream);
  csr_hist<<<NE / 256, 256, 0, stream>>>(receivers, deg);
  csr_scan<<<1, 256, 0, stream>>>(deg, start, cursor);
  csr_scatter<<<NE / 256, 256, 0, stream>>>(receivers, cursor, elist);
  csr_sort<<<NN / 256, 256, 0, stream>>>(start, elist);

  pack_w<<<256, 256, 0, stream>>>(f(6), en_W1p, 256, 256, 1);
  pack_w<<<256, 256, 0, stream>>>(f(12), ee_W1p, 256, 256, 1);
  pack_w<<<1024, 256, 0, stream>>>(f(16), pe_W0p, 768, 256, 4);
  pack_w<<<512, 256, 0, stream>>>(f(18), pe_W1p, 256, 256, 4);
  pack_w<<<1024, 256, 0, stream>>>(f(22), pn_W0p, 512, 256, 4);
  pack_w<<<512, 256, 0, stream>>>(f(24), pn_W1p, 256, 256, 4);
  pack_w<<<256, 256, 0, stream>>>(f(28), dn_W0p, 256, 256, 1);
  pack_w<<<128, 256, 0, stream>>>(f(30), dn_W1p, 256, 128, 1);

  embed_mfma<3, true><<<NN / 64, 256, 0, stream>>>(
      node_feats, f(4), f(5), en_W1p, f(7), f(8), f(9), nodes_f, nodes_b);
  embed_mfma<4, false><<<NE / 64, 256, 0, stream>>>(
      edge_feats, f(10), f(11), ee_W1p, f(13), f(14), f(15), nullptr, edges_b);

  for (int s = 0; s < SSTEPS; ++s) {
    edge_step_mfma<<<NE / 64, 256, 0, stream>>>(
        nodes_b, edges_b, new_e, senders, receivers,
        pe_W0p + (size_t)s * 768 * 256, f(17) + (size_t)s * 256,
        pe_W1p + (size_t)s * 65536, f(19) + (size_t)s * 256,
        f(20) + (size_t)s * 256, f(21) + (size_t)s * 256);
    agg_gather<<<NN / 64, 256, 0, stream>>>(new_e, start, elist, agg_b);
    node_step_mfma<<<NN / 64, 256, 0, stream>>>(
        nodes_f, nodes_b, agg_b, pn_W0p + (size_t)s * 512 * 256,
        f(23) + (size_t)s * 256, pn_W1p + (size_t)s * 65536,
        f(25) + (size_t)s * 256, f(26) + (size_t)s * 256,
        f(27) + (size_t)s * 256);
  }

  decoder_mfma<<<NN / 64, 256, 0, stream>>>(nodes_b, dn_W0p, f(29), dn_W1p,
                                            f(31), (float*)d_out);
}

// Round 7
// 1041.146 us; speedup vs baseline: 1.3159x; 1.3159x over previous
//
#include <hip/hip_runtime.h>
#include <hip/hip_bf16.h>

#define NN 16384
#define NE 131072
#define L 256
#define SSTEPS 4
#define OUTD 128

typedef __attribute__((ext_vector_type(8))) short bf16x8;
typedef __attribute__((ext_vector_type(4))) float f32x4;

__device__ __forceinline__ short f2bs(float f) {
  unsigned u = __builtin_bit_cast(unsigned, f);
  u = (u + 0x7fffu + ((u >> 16) & 1u)) >> 16;
  return (short)u;
}
__device__ __forceinline__ float bs2f(short s) {
  unsigned u = ((unsigned)(unsigned short)s) << 16;
  return __builtin_bit_cast(float, u);
}
// RNE pack of two f32 into (lo | hi<<16) bf16 pair — one VALU op.
__device__ __forceinline__ unsigned cvt_pk_bf16(float lo, float hi) {
  unsigned r;
  asm("v_cvt_pk_bf16_f32 %0, %1, %2" : "=v"(r) : "v"(lo), "v"(hi));
  return r;
}
__device__ __forceinline__ bf16x8 pack_bf16x8(const float v[8]) {
  union { unsigned u[4]; bf16x8 b; } r;
#pragma unroll
  for (int k = 0; k < 4; ++k) r.u[k] = cvt_pk_bf16(v[2 * k], v[2 * k + 1]);
  return r.b;
}

// Store one 16x16 C-tile (f32x4 per lane) into swizzled bf16 LDS [64][256]
// (row stride 512B). byte ^= (row&7)<<4.
__device__ __forceinline__ void store_tile(short* hs, int l, int mi, int nb,
                                           f32x4 v) {
  const int lm = l & 15, g = l >> 4;
#pragma unroll
  for (int i = 0; i < 4; ++i) {
    const float part = __shfl_xor(v[i], 1);
    if ((l & 1) == 0) {
      const int row = mi * 16 + g * 4 + i;
      const int col = nb + lm;  // even
      const int off = (row * 512 + col * 2) ^ ((row & 7) << 4);
      *(unsigned*)((char*)hs + off) = cvt_pk_bf16(v[i], part);
    }
  }
}

// GEMM from swizzled bf16 LDS h[64][256] (512B stride) x packed W (K=256).
template <int NT>
__device__ __forceinline__ void gemm2_lds(const short* __restrict__ Wp,
                                          int Ncols, const short* hs, int n0,
                                          int l, f32x4 acc[4][NT]) {
  const int lm = l & 15, g = l >> 4;
#pragma unroll
  for (int kc = 0; kc < 8; ++kc) {
    bf16x8 a[4];
#pragma unroll
    for (int mi = 0; mi < 4; ++mi) {
      const int row = mi * 16 + lm;
      const int off = (row * 512 + kc * 64 + g * 16) ^ ((row & 7) << 4);
      a[mi] = *(const bf16x8*)((const char*)hs + off);
    }
#pragma unroll
    for (int ni = 0; ni < NT; ++ni) {
      const int n = n0 + ni * 16 + lm;
      bf16x8 b = *(const bf16x8*)(Wp + ((size_t)kc * Ncols + n) * 32 + g * 8);
#pragma unroll
      for (int mi = 0; mi < 4; ++mi)
        acc[mi][ni] =
            __builtin_amdgcn_mfma_f32_16x16x32_bf16(a[mi], b, acc[mi][ni], 0, 0, 0);
    }
  }
}

// Pack fp32 weight [K][N] (cnt stacked) into bf16 Wp[k/32][n][k%32].
__global__ void pack_w(const float* __restrict__ src, short* __restrict__ dst,
                       int K, int N, int cnt) {
  const size_t total = (size_t)K * N * cnt;
  for (size_t i = (size_t)blockIdx.x * blockDim.x + threadIdx.x; i < total;
       i += (size_t)gridDim.x * blockDim.x) {
    const size_t mat = i / ((size_t)K * N);
    const int rem = (int)(i - mat * (size_t)K * N);
    const int k = rem / N, n = rem - k * N;
    dst[mat * (size_t)K * N + ((size_t)(k >> 5) * N + n) * 32 + (k & 31)] =
        f2bs(src[i]);
  }
}

// Layer-1 MFMA over one staged 128-K chunk in As (row stride 256B, swizzled).
__device__ __forceinline__ void mfma_chunk(const short* __restrict__ As,
                                           const short* __restrict__ W0p,
                                           int kcg_base, int w, int l,
                                           f32x4 acc[4][4]) {
  const int lm = l & 15, g = l >> 4;
#pragma unroll
  for (int kc = 0; kc < 4; ++kc) {
    bf16x8 a[4];
#pragma unroll
    for (int mi = 0; mi < 4; ++mi) {
      const int row = mi * 16 + lm;
      const int off = (row * 256 + kc * 64 + g * 16) ^ ((row & 7) << 4);
      a[mi] = *(const bf16x8*)((const char*)As + off);
    }
#pragma unroll
    for (int ni = 0; ni < 4; ++ni) {
      const int n = w * 64 + ni * 16 + lm;
      bf16x8 b =
          *(const bf16x8*)(W0p + ((size_t)(kcg_base + kc) * L + n) * 32 + g * 8);
#pragma unroll
      for (int mi = 0; mi < 4; ++mi)
        acc[mi][ni] =
            __builtin_amdgcn_mfma_f32_16x16x32_bf16(a[mi], b, acc[mi][ni], 0, 0, 0);
    }
  }
}

// ---------------------------------------------------------------------------
// CSR build (deterministic: per-node lists sorted ascending by edge id)
// ---------------------------------------------------------------------------
__global__ void csr_hist(const int* __restrict__ recv, int* __restrict__ deg) {
  const int e = blockIdx.x * 256 + threadIdx.x;
  atomicAdd(&deg[recv[e]], 1);
}
__global__ __launch_bounds__(256) void csr_scan(const int* __restrict__ deg,
                                                int* __restrict__ start,
                                                int* __restrict__ cursor) {
  __shared__ int part[256];
  const int t = threadIdx.x;
  int s = 0;
  for (int i = 0; i < NN / 256; ++i) s += deg[t * (NN / 256) + i];
  part[t] = s;
  __syncthreads();
  if (t == 0) {
    int acc = 0;
    for (int i = 0; i < 256; ++i) {
      const int v = part[i];
      part[i] = acc;
      acc += v;
    }
  }
  __syncthreads();
  int acc = part[t];
  for (int i = 0; i < NN / 256; ++i) {
    const int n = t * (NN / 256) + i;
    start[n] = acc;
    cursor[n] = acc;
    acc += deg[n];
  }
  if (t == 255) start[NN] = acc;
}
__global__ void csr_scatter(const int* __restrict__ recv,
                            int* __restrict__ cursor, int* __restrict__ elist) {
  const int e = blockIdx.x * 256 + threadIdx.x;
  const int p = atomicAdd(&cursor[recv[e]], 1);
  elist[p] = e;
}
__global__ void csr_sort(const int* __restrict__ start, int* __restrict__ elist) {
  const int n = blockIdx.x * blockDim.x + threadIdx.x;
  if (n >= NN) return;
  const int b = start[n], e = start[n + 1];
  for (int i = b + 1; i < e; ++i) {
    const int v = elist[i];
    int j = i - 1;
    while (j >= b && elist[j] > v) {
      elist[j + 1] = elist[j];
      --j;
    }
    elist[j + 1] = v;
  }
}

// ---------------------------------------------------------------------------
// agg gather: agg_b[n] = bf16( sum_{e in CSR[n]} new_e[e] )  (fp32 accum)
// ---------------------------------------------------------------------------
__global__ __launch_bounds__(256) void agg_gather(
    const short* __restrict__ new_e, const int* __restrict__ start,
    const int* __restrict__ elist, short* __restrict__ agg_b) {
  const int t = threadIdx.x, w = t >> 6, l = t & 63;
  const int half = l >> 5, lc = l & 31;
  const int n0 = blockIdx.x * 64;
  for (int i = 0; i < 8; ++i) {
    const int n = n0 + w * 16 + i * 2 + half;
    const int b = start[n], e = start[n + 1];
    float acc[8] = {0.f, 0.f, 0.f, 0.f, 0.f, 0.f, 0.f, 0.f};
#pragma unroll 2
    for (int j = b; j < e; ++j) {
      const int eid = elist[j];
      const bf16x8 v = *(const bf16x8*)(new_e + (size_t)eid * L + lc * 8);
#pragma unroll
      for (int k = 0; k < 8; ++k) acc[k] += bs2f(v[k]);
    }
    *(bf16x8*)(agg_b + (size_t)n * L + lc * 8) = pack_bf16x8(acc);
  }
}

// ---------------------------------------------------------------------------
// Epilogue LN: thread owns rows p*16+tr (p=0..3), cols seg*8 and 128+seg*8.
// Row stats via 16-lane shfl tree (lanes sharing l>>4 hold one row).
// ---------------------------------------------------------------------------
__device__ __forceinline__ void ln_row(const short* smem, int row, int seg,
                                       const float lsv[16], const float lbv[16],
                                       float ne[16]) {
  const int off0 = (row * 512 + seg * 16) ^ ((row & 7) << 4);
  const int off1 = (row * 512 + 256 + seg * 16) ^ ((row & 7) << 4);
  const bf16x8 y0 = *(const bf16x8*)((const char*)smem + off0);
  const bf16x8 y1 = *(const bf16x8*)((const char*)smem + off1);
  float v[16];
#pragma unroll
  for (int k = 0; k < 8; ++k) {
    v[k] = bs2f(y0[k]);
    v[8 + k] = bs2f(y1[k]);
  }
  float s = 0.f;
#pragma unroll
  for (int k = 0; k < 16; ++k) s += v[k];
#pragma unroll
  for (int o = 1; o < 16; o <<= 1) s += __shfl_xor(s, o);
  const float mu = s * (1.f / 256.f);
  float sq = 0.f;
#pragma unroll
  for (int k = 0; k < 16; ++k) {
    const float d = v[k] - mu;
    sq += d * d;
  }
#pragma unroll
  for (int o = 1; o < 16; o <<= 1) sq += __shfl_xor(sq, o);
  const float rstd = rsqrtf(sq * (1.f / 256.f) + 1e-6f);
#pragma unroll
  for (int k = 0; k < 16; ++k) ne[k] = (v[k] - mu) * rstd * lsv[k] + lbv[k];
}

__device__ __forceinline__ void load16(const float* __restrict__ p, int seg,
                                       float d[16]) {
  const float4 a0 = *(const float4*)(p + seg * 8);
  const float4 a1 = *(const float4*)(p + seg * 8 + 4);
  const float4 a2 = *(const float4*)(p + 128 + seg * 8);
  const float4 a3 = *(const float4*)(p + 128 + seg * 8 + 4);
  d[0] = a0.x; d[1] = a0.y; d[2] = a0.z; d[3] = a0.w;
  d[4] = a1.x; d[5] = a1.y; d[6] = a1.z; d[7] = a1.w;
  d[8] = a2.x; d[9] = a2.y; d[10] = a2.z; d[11] = a2.w;
  d[12] = a3.x; d[13] = a3.y; d[14] = a3.z; d[15] = a3.w;
}

// ---------------------------------------------------------------------------
// Edge step: X=[edges_b|nodes_b[snd]|nodes_b[rcv]] (768 bf16) -> MFMA MLP ->
// LN -> edges_b += ne (residual from regs); new_e = ne. 2-deep prefetch.
// ---------------------------------------------------------------------------
__global__ __launch_bounds__(256) void edge_step_mfma(
    const short* __restrict__ nodes_b, short* __restrict__ edges_b,
    short* __restrict__ new_e, const int* __restrict__ senders,
    const int* __restrict__ receivers, const short* __restrict__ W0p,
    const float* __restrict__ b0, const short* __restrict__ W1p,
    const float* __restrict__ b1, const float* __restrict__ ls,
    const float* __restrict__ lb) {
  __shared__ short smem[64 * 256];  // 32KB: As[2][64][128] then h/y[64][256]
  __shared__ int sn_s[64], rc_s[64];
  const int t = threadIdx.x, w = t >> 6, l = t & 63;
  const int lm = l & 15;
  const int tr = t >> 4, seg = t & 15;
  const int e0 = blockIdx.x * 64;
  short* As0 = smem;
  short* As1 = smem + 8192;

  if (t < 64) sn_s[t] = senders[e0 + t];
  else if (t < 128) rc_s[t - 64] = receivers[e0 + t - 64];

  bf16x8 o[2][4];
  bf16x8 old0[4], old1[4];  // residual stash (edge cols 0..127 / 128..255)
  // prologue: chunks 0,1 (edges)
#pragma unroll
  for (int p = 0; p < 4; ++p) {
    o[0][p] = *(const bf16x8*)(edges_b + (size_t)(e0 + p * 16 + tr) * L + seg * 8);
    old0[p] = o[0][p];
  }
#pragma unroll
  for (int p = 0; p < 4; ++p) {
    const int row = p * 16 + tr;
    const int off = (row * 256 + seg * 16) ^ ((row & 7) << 4);
    *(bf16x8*)((char*)As0 + off) = o[0][p];
  }
#pragma unroll
  for (int p = 0; p < 4; ++p) {
    o[1][p] =
        *(const bf16x8*)(edges_b + (size_t)(e0 + p * 16 + tr) * L + 128 + seg * 8);
    old1[p] = o[1][p];
  }
  __syncthreads();

  f32x4 acc[4][4] = {};
#pragma unroll
  for (int c = 0; c < 6; ++c) {
    if (c + 2 < 6) {  // 2-deep: issue chunk c+2 loads (node gathers)
      const int cn = c + 2;  // 2..5
      const int* ridx = (cn < 4) ? sn_s : rc_s;
      const int cb = (cn & 1) * 128;
#pragma unroll
      for (int p = 0; p < 4; ++p) {
        const size_t gr = (size_t)ridx[p * 16 + tr];
        o[c & 1][p] = *(const bf16x8*)(nodes_b + gr * L + cb + seg * 8);
      }
    }
    mfma_chunk((c & 1) ? As1 : As0, W0p, c * 4, w, l, acc);
    if (c + 1 < 6) {  // write chunk c+1 (loaded two iters ago)
      short* dbuf = (c & 1) ? As0 : As1;
#pragma unroll
      for (int p = 0; p < 4; ++p) {
        const int row = p * 16 + tr;
        const int off = (row * 256 + seg * 16) ^ ((row & 7) << 4);
        *(bf16x8*)((char*)dbuf + off) = o[(c + 1) & 1][p];
      }
    }
    __syncthreads();
  }

  // bias + relu -> h in smem (viewed as [64][256], 512B stride)
#pragma unroll
  for (int ni = 0; ni < 4; ++ni) {
    const float bia = b0[w * 64 + ni * 16 + lm];
#pragma unroll
    for (int mi = 0; mi < 4; ++mi) {
      f32x4 v = acc[mi][ni];
#pragma unroll
      for (int i = 0; i < 4; ++i) v[i] = fmaxf(v[i] + bia, 0.f);
      store_tile(smem, l, mi, w * 64 + ni * 16, v);
    }
  }
  __syncthreads();

  f32x4 acc2[4][4] = {};
  gemm2_lds<4>(W1p, L, smem, w * 64, l, acc2);
  __syncthreads();  // all h reads done; reuse smem for y
#pragma unroll
  for (int ni = 0; ni < 4; ++ni) {
    const float bia = b1[w * 64 + ni * 16 + lm];
#pragma unroll
    for (int mi = 0; mi < 4; ++mi) {
      f32x4 v = acc2[mi][ni];
#pragma unroll
      for (int i = 0; i < 4; ++i) v[i] += bia;
      store_tile(smem, l, mi, w * 64 + ni * 16, v);
    }
  }
  __syncthreads();

  // epilogue: LN + residual + stores, no extra barriers
  float lsv[16], lbv[16];
  load16(ls, seg, lsv);
  load16(lb, seg, lbv);
#pragma unroll
  for (int p = 0; p < 4; ++p) {
    const int row = p * 16 + tr;
    float ne[16];
    ln_row(smem, row, seg, lsv, lbv, ne);
    const size_t e = (size_t)(e0 + row);
    *(bf16x8*)(new_e + e * L + seg * 8) = pack_bf16x8(ne);
    *(bf16x8*)(new_e + e * L + 128 + seg * 8) = pack_bf16x8(ne + 8);
    float r0[8], r1[8];
#pragma unroll
    for (int k = 0; k < 8; ++k) {
      r0[k] = bs2f(old0[p][k]) + ne[k];
      r1[k] = bs2f(old1[p][k]) + ne[8 + k];
    }
    *(bf16x8*)(edges_b + e * L + seg * 8) = pack_bf16x8(r0);
    *(bf16x8*)(edges_b + e * L + 128 + seg * 8) = pack_bf16x8(r1);
  }
}

// ---------------------------------------------------------------------------
// Node step: X=[nodes_b|agg_b] (512 bf16) -> MFMA MLP -> LN ->
// nodes_f += ne (fp32 master) ; nodes_b = bf16(nodes_f). 2-deep prefetch.
// ---------------------------------------------------------------------------
__global__ __launch_bounds__(256) void node_step_mfma(
    float* __restrict__ nodes_f, short* __restrict__ nodes_b,
    const short* __restrict__ agg_b, const short* __restrict__ W0p,
    const float* __restrict__ b0, const short* __restrict__ W1p,
    const float* __restrict__ b1, const float* __restrict__ ls,
    const float* __restrict__ lb) {
  __shared__ short smem[64 * 256];
  const int t = threadIdx.x, w = t >> 6, l = t & 63;
  const int lm = l & 15;
  const int tr = t >> 4, seg = t & 15;
  const int n0 = blockIdx.x * 64;
  short* As0 = smem;
  short* As1 = smem + 8192;

  bf16x8 o[2][4];
#pragma unroll
  for (int p = 0; p < 4; ++p)
    o[0][p] = *(const bf16x8*)(nodes_b + (size_t)(n0 + p * 16 + tr) * L + seg * 8);
#pragma unroll
  for (int p = 0; p < 4; ++p) {
    const int row = p * 16 + tr;
    const int off = (row * 256 + seg * 16) ^ ((row & 7) << 4);
    *(bf16x8*)((char*)As0 + off) = o[0][p];
  }
#pragma unroll
  for (int p = 0; p < 4; ++p)
    o[1][p] =
        *(const bf16x8*)(nodes_b + (size_t)(n0 + p * 16 + tr) * L + 128 + seg * 8);
  __syncthreads();

  f32x4 acc[4][4] = {};
#pragma unroll
  for (int c = 0; c < 4; ++c) {
    if (c + 2 < 4) {  // chunks 2,3 = agg cols 0-127 / 128-255
      const int cb = ((c + 2) & 1) * 128;
#pragma unroll
      for (int p = 0; p < 4; ++p)
        o[c & 1][p] =
            *(const bf16x8*)(agg_b + (size_t)(n0 + p * 16 + tr) * L + cb + seg * 8);
    }
    mfma_chunk((c & 1) ? As1 : As0, W0p, c * 4, w, l, acc);
    if (c + 1 < 4) {
      short* dbuf = (c & 1) ? As0 : As1;
#pragma unroll
      for (int p = 0; p < 4; ++p) {
        const int row = p * 16 + tr;
        const int off = (row * 256 + seg * 16) ^ ((row & 7) << 4);
        *(bf16x8*)((char*)dbuf + off) = o[(c + 1) & 1][p];
      }
    }
    __syncthreads();
  }

#pragma unroll
  for (int ni = 0; ni < 4; ++ni) {
    const float bia = b0[w * 64 + ni * 16 + lm];
#pragma unroll
    for (int mi = 0; mi < 4; ++mi) {
      f32x4 v = acc[mi][ni];
#pragma unroll
      for (int i = 0; i < 4; ++i) v[i] = fmaxf(v[i] + bia, 0.f);
      store_tile(smem, l, mi, w * 64 + ni * 16, v);
    }
  }
  __syncthreads();

  f32x4 acc2[4][4] = {};
  gemm2_lds<4>(W1p, L, smem, w * 64, l, acc2);
  __syncthreads();
#pragma unroll
  for (int ni = 0; ni < 4; ++ni) {
    const float bia = b1[w * 64 + ni * 16 + lm];
#pragma unroll
    for (int mi = 0; mi < 4; ++mi) {
      f32x4 v = acc2[mi][ni];
#pragma unroll
      for (int i = 0; i < 4; ++i) v[i] += bia;
      store_tile(smem, l, mi, w * 64 + ni * 16, v);
    }
  }
  __syncthreads();

  float lsv[16], lbv[16];
  load16(ls, seg, lsv);
  load16(lb, seg, lbv);
#pragma unroll
  for (int p = 0; p < 4; ++p) {
    const int row = p * 16 + tr;
    float ne[16];
    ln_row(smem, row, seg, lsv, lbv, ne);
    const size_t n = (size_t)(n0 + row);
    float* nf = nodes_f + n * L;
    float fv[16];
    load16(nf, seg, fv);
    float nv[16];
#pragma unroll
    for (int k = 0; k < 16; ++k) nv[k] = fv[k] + ne[k];
    *(float4*)(nf + seg * 8) = make_float4(nv[0], nv[1], nv[2], nv[3]);
    *(float4*)(nf + seg * 8 + 4) = make_float4(nv[4], nv[5], nv[6], nv[7]);
    *(float4*)(nf + 128 + seg * 8) = make_float4(nv[8], nv[9], nv[10], nv[11]);
    *(float4*)(nf + 128 + seg * 8 + 4) = make_float4(nv[12], nv[13], nv[14], nv[15]);
    *(bf16x8*)(nodes_b + n * L + seg * 8) = pack_bf16x8(nv);
    *(bf16x8*)(nodes_b + n * L + 128 + seg * 8) = pack_bf16x8(nv + 8);
  }
}

// ---------------------------------------------------------------------------
// Embedder: layer1 (K1->256, VALU) -> h in LDS -> MFMA layer2 -> LN -> dst
// ---------------------------------------------------------------------------
template <int K1, bool WF32>
__global__ __launch_bounds__(256) void embed_mfma(
    const float* __restrict__ x, const float* __restrict__ W0,
    const float* __restrict__ b0, const short* __restrict__ W1p,
    const float* __restrict__ b1, const float* __restrict__ ls,
    const float* __restrict__ lb, float* __restrict__ dst_f,
    short* __restrict__ dst_b) {
  __shared__ short hs[64 * 256];
  __shared__ float xs[64][K1];
  const int t = threadIdx.x, w = t >> 6, l = t & 63;
  const int lm = l & 15;
  const int tr = t >> 4, seg = t & 15;
  const int r0 = blockIdx.x * 64;

  if (t < 64 * K1) xs[t / K1][t % K1] = x[(size_t)r0 * K1 + t];
  __syncthreads();

  float wc[K1];
#pragma unroll
  for (int k = 0; k < K1; ++k) wc[k] = W0[k * L + t];
  const float bb = b0[t];
  for (int r = 0; r < 64; ++r) {
    float h = bb;
#pragma unroll
    for (int k = 0; k < K1; ++k) h = fmaf(xs[r][k], wc[k], h);
    h = fmaxf(h, 0.f);
    const int off = (r * 512 + t * 2) ^ ((r & 7) << 4);
    *(short*)((char*)hs + off) = f2bs(h);
  }
  __syncthreads();

  f32x4 acc2[4][4] = {};
  gemm2_lds<4>(W1p, L, hs, w * 64, l, acc2);
  __syncthreads();
#pragma unroll
  for (int ni = 0; ni < 4; ++ni) {
    const float bia = b1[w * 64 + ni * 16 + lm];
#pragma unroll
    for (int mi = 0; mi < 4; ++mi) {
      f32x4 v = acc2[mi][ni];
#pragma unroll
      for (int i = 0; i < 4; ++i) v[i] += bia;
      store_tile(hs, l, mi, w * 64 + ni * 16, v);
    }
  }
  __syncthreads();

  float lsv[16], lbv[16];
  load16(ls, seg, lsv);
  load16(lb, seg, lbv);
#pragma unroll
  for (int p = 0; p < 4; ++p) {
    const int row = p * 16 + tr;
    float ne[16];
    ln_row(hs, row, seg, lsv, lbv, ne);
    const size_t n = (size_t)(r0 + row);
    *(bf16x8*)(dst_b + n * L + seg * 8) = pack_bf16x8(ne);
    *(bf16x8*)(dst_b + n * L + 128 + seg * 8) = pack_bf16x8(ne + 8);
    if (WF32) {
      float* df = dst_f + n * L;
      *(float4*)(df + seg * 8) = make_float4(ne[0], ne[1], ne[2], ne[3]);
      *(float4*)(df + seg * 8 + 4) = make_float4(ne[4], ne[5], ne[6], ne[7]);
      *(float4*)(df + 128 + seg * 8) = make_float4(ne[8], ne[9], ne[10], ne[11]);
      *(float4*)(df + 128 + seg * 8 + 4) =
          make_float4(ne[12], ne[13], ne[14], ne[15]);
    }
  }
}

// ---------------------------------------------------------------------------
// Decoder: nodes_b (256 bf16) -> MFMA 256 relu -> MFMA 128 -> out (fp32)
// ---------------------------------------------------------------------------
__global__ __launch_bounds__(256) void decoder_mfma(
    const short* __restrict__ nodes_b, const short* __restrict__ W0p,
    const float* __restrict__ b0, const short* __restrict__ W1p,
    const float* __restrict__ b1, float* __restrict__ out) {
  __shared__ short hs[64 * 256];
  const int t = threadIdx.x, w = t >> 6, l = t & 63;
  const int lm = l & 15, g = l >> 4;
  const int n0 = blockIdx.x * 64;

  const short* baseA[4];
#pragma unroll
  for (int mi = 0; mi < 4; ++mi)
    baseA[mi] = nodes_b + (size_t)(n0 + mi * 16 + lm) * L;

  f32x4 acc[4][4] = {};
#pragma unroll
  for (int kc = 0; kc < 8; ++kc) {
    const int koff = kc * 32 + g * 8;
    bf16x8 a[4];
#pragma unroll
    for (int mi = 0; mi < 4; ++mi) a[mi] = *(const bf16x8*)(baseA[mi] + koff);
#pragma unroll
    for (int ni = 0; ni < 4; ++ni) {
      const int n = w * 64 + ni * 16 + lm;
      bf16x8 b = *(const bf16x8*)(W0p + ((size_t)kc * L + n) * 32 + g * 8);
#pragma unroll
      for (int mi = 0; mi < 4; ++mi)
        acc[mi][ni] = __builtin_amdgcn_mfma_f32_16x16x32_bf16(a[mi], b,
                                                             acc[mi][ni],
                                                             0, 0, 0);
    }
  }
#pragma unroll
  for (int ni = 0; ni < 4; ++ni) {
    const float bia = b0[w * 64 + ni * 16 + lm];
#pragma unroll
    for (int mi = 0; mi < 4; ++mi) {
      f32x4 v = acc[mi][ni];
#pragma unroll
      for (int i = 0; i < 4; ++i) v[i] = fmaxf(v[i] + bia, 0.f);
      store_tile(hs, l, mi, w * 64 + ni * 16, v);
    }
  }
  __syncthreads();

  f32x4 acc2[4][2] = {};
  gemm2_lds<2>(W1p, OUTD, hs, w * 32, l, acc2);

  float b14[2];
#pragma unroll
  for (int ni = 0; ni < 2; ++ni) b14[ni] = b1[w * 32 + ni * 16 + lm];
#pragma unroll
  for (int mi = 0; mi < 4; ++mi)
#pragma unroll
    for (int ni = 0; ni < 2; ++ni)
#pragma unroll
      for (int i = 0; i < 4; ++i) {
        const int row = n0 + mi * 16 + g * 4 + i;
        const int col = w * 32 + ni * 16 + lm;
        out[(size_t)row * OUTD + col] = acc2[mi][ni][i] + b14[ni];
      }
}

// ---------------------------------------------------------------------------
extern "C" void kernel_launch(void* const* d_in, const int* in_sizes, int n_in,
                              void* d_out, int out_size, void* d_ws,
                              size_t ws_size, hipStream_t stream) {
  const float* node_feats = (const float*)d_in[0];
  const float* edge_feats = (const float*)d_in[1];
  const int* senders = (const int*)d_in[2];
  const int* receivers = (const int*)d_in[3];
  auto f = [&](int i) { return (const float*)d_in[i]; };

  char* p = (char*)d_ws;
  auto alloc = [&](size_t bytes) {
    char* q = p;
    p += (bytes + 255) & ~(size_t)255;
    return q;
  };
  float* nodes_f = (float*)alloc((size_t)NN * L * 4);   // 16 MB
  short* nodes_b = (short*)alloc((size_t)NN * L * 2);   // 8 MB
  short* edges_b = (short*)alloc((size_t)NE * L * 2);   // 67 MB
  short* new_e = (short*)alloc((size_t)NE * L * 2);     // 67 MB
  short* agg_b = (short*)alloc((size_t)NN * L * 2);     // 8 MB
  int* deg = (int*)alloc((size_t)NN * 4);
  int* start = (int*)alloc((size_t)(NN + 16) * 4);
  int* cursor = (int*)alloc((size_t)NN * 4);
  int* elist = (int*)alloc((size_t)NE * 4);
  short* en_W1p = (short*)alloc(65536 * 2);
  short* ee_W1p = (short*)alloc(65536 * 2);
  short* pe_W0p = (short*)alloc((size_t)4 * 768 * 256 * 2);
  short* pe_W1p = (short*)alloc((size_t)4 * 65536 * 2);
  short* pn_W0p = (short*)alloc((size_t)4 * 512 * 256 * 2);
  short* pn_W1p = (short*)alloc((size_t)4 * 65536 * 2);
  short* dn_W0p = (short*)alloc(65536 * 2);
  short* dn_W1p = (short*)alloc(32768 * 2);

  // CSR build (deterministic after per-node sort)
  hipMemsetAsync(deg, 0, (size_t)NN * 4, stream);
  csr_hist<<<NE / 256, 256, 0, stream>>>(receivers, deg);
  csr_scan<<<1, 256, 0, stream>>>(deg, start, cursor);
  csr_scatter<<<NE / 256, 256, 0, stream>>>(receivers, cursor, elist);
  csr_sort<<<NN / 256, 256, 0, stream>>>(start, elist);

  pack_w<<<256, 256, 0, stream>>>(f(6), en_W1p, 256, 256, 1);
  pack_w<<<256, 256, 0, stream>>>(f(12), ee_W1p, 256, 256, 1);
  pack_w<<<1024, 256, 0, stream>>>(f(16), pe_W0p, 768, 256, 4);
  pack_w<<<512, 256, 0, stream>>>(f(18), pe_W1p, 256, 256, 4);
  pack_w<<<1024, 256, 0, stream>>>(f(22), pn_W0p, 512, 256, 4);
  pack_w<<<512, 256, 0, stream>>>(f(24), pn_W1p, 256, 256, 4);
  pack_w<<<256, 256, 0, stream>>>(f(28), dn_W0p, 256, 256, 1);
  pack_w<<<128, 256, 0, stream>>>(f(30), dn_W1p, 256, 128, 1);

  embed_mfma<3, true><<<NN / 64, 256, 0, stream>>>(
      node_feats, f(4), f(5), en_W1p, f(7), f(8), f(9), nodes_f, nodes_b);
  embed_mfma<4, false><<<NE / 64, 256, 0, stream>>>(
      edge_feats, f(10), f(11), ee_W1p, f(13), f(14), f(15), nullptr, edges_b);

  for (int s = 0; s < SSTEPS; ++s) {
    edge_step_mfma<<<NE / 64, 256, 0, stream>>>(
        nodes_b, edges_b, new_e, senders, receivers,
        pe_W0p + (size_t)s * 768 * 256, f(17) + (size_t)s * 256,
        pe_W1p + (size_t)s * 65536, f(19) + (size_t)s * 256,
        f(20) + (size_t)s * 256, f(21) + (size_t)s * 256);
    agg_gather<<<NN / 64, 256, 0, stream>>>(new_e, start, elist, agg_b);
    node_step_mfma<<<NN / 64, 256, 0, stream>>>(
        nodes_f, nodes_b, agg_b, pn_W0p + (size_t)s * 512 * 256,
        f(23) + (size_t)s * 256, pn_W1p + (size_t)s * 65536,
        f(25) + (size_t)s * 256, f(26) + (size_t)s * 256,
        f(27) + (size_t)s * 256);
  }

  decoder_mfma<<<NN / 64, 256, 0, stream>>>(nodes_b, dn_W0p, f(29), dn_W1p,
                                            f(31), (float*)d_out);
}